// Round 13
// baseline (577.248 us; speedup 1.0000x reference)
//
#include <hip/hip_runtime.h>
#include <math.h>

// HashGrid: 8 LODs, hashed trilinear interp, 1 feature/entry, summed over LODs.
// LODS  = [17, 27, 44, 71, 116, 191, 313, res7(host-computed, 512 or 513)]
// SIZES = [4913, 19683, 85184, 357911, 2^19, 2^19, 2^19, 2^19]
// codebook layout: [8][524288][1] float32.
//
// R13: spatial bucketing. Wall = TA/TCP address throughput (~2.2-2.8 cyc per
// random lane-address, R5-R12). Counting-sort points into 32^3 spatial
// buckets (~61 pts ~ 1 wave per bucket) so a wave's gathers at LOD0..4 hit
// few distinct dwords -> TA coalesces them. LOD5..7 remain random (sparse)
// with the x-pair merge. Pipeline: convert -> zero-hist -> hist -> scan ->
// scatter(sorted float4 w/ idx in .w) -> main (scatter out[orig_idx]).
// Deterministic output: per-point arithmetic identical regardless of order.
// Tiers: ws>=37.3MB sort path; ws>=5.13MB direct (R12) path; else f32.

static constexpr unsigned CB_STRIDE = 524288u;
static constexpr int S0 = 4913;    // 17^3 (LDS staging, direct tier)
static constexpr int S1 = 19683;   // 27^3
// packed bf16 table element offsets (all EVEN, 4B-aligned)
static constexpr unsigned O0 = 0;        // 4913
static constexpr unsigned O1 = 4928;     // 19683
static constexpr unsigned O2 = 24640;    // 85184
static constexpr unsigned O3 = 109824;   // 357911
static constexpr unsigned O4 = 467744;   // 524288
static constexpr unsigned O5 = 992032;   // 524288
static constexpr unsigned O6 = 1516320;  // 524288
static constexpr unsigned O7 = 2040608;  // -> end 2564896 u16 = 5129792 B
static constexpr unsigned TBL_BYTES = 5129792u;
static constexpr unsigned NB = 32768u;            // 32^3 buckets
static constexpr unsigned OFF_H = TBL_BYTES;      // hist/offsets, 131072 B
static constexpr unsigned OFF_P = OFF_H + NB * 4u; // sorted float4 base (16B aligned)
static constexpr size_t WS_MID_BYTES  = TBL_BYTES;
__host__ __device__ static inline size_t ws_full_bytes(int n) {
    return (size_t)OFF_P + (size_t)n * 16u;
}

__device__ __forceinline__ unsigned short f32_to_bf16_rne(float f) {
    unsigned u = __float_as_uint(f);
    u = (u + 0x7FFFu + ((u >> 16) & 1u)) >> 16;
    return (unsigned short)u;
}
__device__ __forceinline__ float bf16_to_f32(unsigned short s) {
    return __uint_as_float(((unsigned)s) << 16);
}

struct I8 { unsigned a0, a1, a2, a3, a4, a5, a6, a7; };
struct R8 { unsigned short v0, v1, v2, v3, v4, v5, v6, v7; };
struct W3 { float x, y, z; };

template <unsigned SIZE>
__device__ __forceinline__ I8 idx8m(float p01x, float p01y, float p01z, int res, W3& fr)
{
    const float rm1 = (float)(res - 1);
    float xx = p01x * rm1, yy = p01y * rm1, zz = p01z * rm1;
    const float cmax = (float)(res - 2);
    float fx = fminf(fmaxf(floorf(xx), 0.0f), cmax);
    float fy = fminf(fmaxf(floorf(yy), 0.0f), cmax);
    float fz = fminf(fmaxf(floorf(zz), 0.0f), cmax);
    fr.x = xx - fx; fr.y = yy - fy; fr.z = zz - fz;
    const unsigned ix = (unsigned)(int)fx;
    const unsigned iy = (unsigned)(int)fy;
    const unsigned iz = (unsigned)(int)fz;
    const unsigned hy0 = iy * 2654435761u, hy1 = hy0 + 2654435761u;
    const unsigned hz0 = iz * 805459861u,  hz1 = hz0 + 805459861u;
    I8 o;
    o.a0 = (ix ^ hy0 ^ hz0) % SIZE;        o.a1 = (ix ^ hy0 ^ hz1) % SIZE;
    o.a2 = (ix ^ hy1 ^ hz0) % SIZE;        o.a3 = (ix ^ hy1 ^ hz1) % SIZE;
    o.a4 = ((ix+1u) ^ hy0 ^ hz0) % SIZE;   o.a5 = ((ix+1u) ^ hy0 ^ hz1) % SIZE;
    o.a6 = ((ix+1u) ^ hy1 ^ hz0) % SIZE;   o.a7 = ((ix+1u) ^ hy1 ^ hz1) % SIZE;
    return o;
}

__device__ __forceinline__ R8 gather8(const unsigned short* __restrict__ t, I8 o)
{
    R8 r;
    r.v0 = t[o.a0]; r.v1 = t[o.a1]; r.v2 = t[o.a2]; r.v3 = t[o.a3];
    r.v4 = t[o.a4]; r.v5 = t[o.a5]; r.v6 = t[o.a6]; r.v7 = t[o.a7];
    return r;
}

__device__ __forceinline__ float acc8(R8 r, W3 f)
{
    const float wx1 = f.x, wx0 = 1.0f - f.x;
    const float wy1 = f.y, wy0 = 1.0f - f.y;
    const float wz1 = f.z, wz0 = 1.0f - f.z;
    const float w00 = wy0 * wz0, w01 = wy0 * wz1;
    const float w10 = wy1 * wz0, w11 = wy1 * wz1;
    const float sx0 = bf16_to_f32(r.v0) * w00 + bf16_to_f32(r.v1) * w01
                    + bf16_to_f32(r.v2) * w10 + bf16_to_f32(r.v3) * w11;
    const float sx1 = bf16_to_f32(r.v4) * w00 + bf16_to_f32(r.v5) * w01
                    + bf16_to_f32(r.v6) * w10 + bf16_to_f32(r.v7) * w11;
    return wx0 * sx0 + wx1 * sx1;
}

// x-pair dword merge. MODE 0 = pow2 2^19; MODE 1 = mod 85184 (even size).
template <int MODE>
__device__ __forceinline__ float lod_merged(float p01x, float p01y, float p01z,
                                            int res,
                                            const unsigned short* __restrict__ t)
{
    const float rm1 = (float)(res - 1);
    float xx = p01x * rm1, yy = p01y * rm1, zz = p01z * rm1;
    const float cmax = (float)(res - 2);
    float fx = fminf(fmaxf(floorf(xx), 0.0f), cmax);
    float fy = fminf(fmaxf(floorf(yy), 0.0f), cmax);
    float fz = fminf(fmaxf(floorf(zz), 0.0f), cmax);
    const float frx = xx - fx, fry = yy - fy, frz = zz - fz;
    const unsigned ix = (unsigned)(int)fx;
    const unsigned iy = (unsigned)(int)fy;
    const unsigned iz = (unsigned)(int)fz;

    const unsigned hy0 = iy * 2654435761u, hy1 = hy0 + 2654435761u;
    const unsigned hz0 = iz * 805459861u,  hz1 = hz0 + 805459861u;

    const unsigned h00 = ix ^ hy0 ^ hz0;
    const unsigned h01 = ix ^ hy0 ^ hz1;
    const unsigned h10 = ix ^ hy1 ^ hz0;
    const unsigned h11 = ix ^ hy1 ^ hz1;

    unsigned E00, E01, E10, E11;
    if (MODE == 0) {
        const unsigned bm = 524286u;  // (2^19-1) & ~1
        E00 = h00 & bm; E01 = h01 & bm; E10 = h10 & bm; E11 = h11 & bm;
    } else {
        E00 = (h00 & ~1u) % 85184u; E01 = (h01 & ~1u) % 85184u;
        E10 = (h10 & ~1u) % 85184u; E11 = (h11 & ~1u) % 85184u;
    }

    const unsigned* t32 = reinterpret_cast<const unsigned*>(t);
    const unsigned p00 = t32[E00 >> 1];
    const unsigned p01 = t32[E01 >> 1];
    const unsigned p10 = t32[E10 >> 1];
    const unsigned p11 = t32[E11 >> 1];

    const bool oddx = (ix & 1u) != 0u;
    unsigned short q00 = 0, q01 = 0, q10 = 0, q11 = 0;
    if (oddx) {
        const unsigned g = ix + 1u;
        if (MODE == 0) {
            const unsigned m = 524287u;
            q00 = t[(g ^ hy0 ^ hz0) & m]; q01 = t[(g ^ hy0 ^ hz1) & m];
            q10 = t[(g ^ hy1 ^ hz0) & m]; q11 = t[(g ^ hy1 ^ hz1) & m];
        } else {
            q00 = t[(g ^ hy0 ^ hz0) % 85184u]; q01 = t[(g ^ hy0 ^ hz1) % 85184u];
            q10 = t[(g ^ hy1 ^ hz0) % 85184u]; q11 = t[(g ^ hy1 ^ hz1) % 85184u];
        }
    }

    const unsigned s00 = h00 & 1u, s01 = h01 & 1u, s10 = h10 & 1u, s11 = h11 & 1u;
    const float a00 = bf16_to_f32((unsigned short)(s00 ? (p00 >> 16) : (p00 & 0xffffu)));
    const float a01 = bf16_to_f32((unsigned short)(s01 ? (p01 >> 16) : (p01 & 0xffffu)));
    const float a10 = bf16_to_f32((unsigned short)(s10 ? (p10 >> 16) : (p10 & 0xffffu)));
    const float a11 = bf16_to_f32((unsigned short)(s11 ? (p11 >> 16) : (p11 & 0xffffu)));
    const float b00 = bf16_to_f32(oddx ? q00 : (unsigned short)(s00 ? (p00 & 0xffffu) : (p00 >> 16)));
    const float b01 = bf16_to_f32(oddx ? q01 : (unsigned short)(s01 ? (p01 & 0xffffu) : (p01 >> 16)));
    const float b10 = bf16_to_f32(oddx ? q10 : (unsigned short)(s10 ? (p10 & 0xffffu) : (p10 >> 16)));
    const float b11 = bf16_to_f32(oddx ? q11 : (unsigned short)(s11 ? (p11 & 0xffffu) : (p11 >> 16)));

    const float wx1 = frx, wx0 = 1.0f - frx;
    const float wy1 = fry, wy0 = 1.0f - fry;
    const float wz1 = frz, wz0 = 1.0f - frz;
    const float w00 = wy0 * wz0, w01 = wy0 * wz1;
    const float w10 = wy1 * wz0, w11 = wy1 * wz1;
    const float sx0 = a00 * w00 + a01 * w01 + a10 * w10 + a11 * w11;
    const float sx1 = b00 * w00 + b01 * w01 + b10 * w10 + b11 * w11;
    return wx0 * sx0 + wx1 * sx1;
}

__device__ __forceinline__ unsigned bucket_key(float p01x, float p01y, float p01z)
{
    int ix = (int)(p01x * 32.0f); ix = ix < 0 ? 0 : (ix > 31 ? 31 : ix);
    int iy = (int)(p01y * 32.0f); iy = iy < 0 ? 0 : (iy > 31 ? 31 : iy);
    int iz = (int)(p01z * 32.0f); iz = iz < 0 ? 0 : (iz > 31 ? 31 : iz);
    return ((unsigned)ix << 10) | ((unsigned)iy << 5) | (unsigned)iz;
}

// ---- prep kernels ----
__global__ __launch_bounds__(1024)
void HashGrid_convert_kernel(const float* __restrict__ codebook,
                             unsigned short* __restrict__ ws)
{
    const int lod = blockIdx.y;  // 0..7
    const int sizes[8] = {4913, 19683, 85184, 357911, 524288, 524288, 524288, 524288};
    const unsigned offs[8] = {O0, O1, O2, O3, O4, O5, O6, O7};
    const int idx = blockIdx.x * 1024 + threadIdx.x;
    if (idx < sizes[lod])
        ws[offs[lod] + idx] = f32_to_bf16_rne(codebook[(unsigned)lod * CB_STRIDE + idx]);
}

__global__ __launch_bounds__(1024)
void HashGrid_zero_hist(unsigned* __restrict__ hist)
{
    const int i = blockIdx.x * 1024 + threadIdx.x;
    if (i < (int)NB) hist[i] = 0u;
}

__global__ __launch_bounds__(256)
void HashGrid_hist_kernel(const float* __restrict__ pts, unsigned* __restrict__ hist, int n)
{
    const int i = blockIdx.x * 256 + threadIdx.x;
    if (i >= n) return;
    const float p01x = pts[3 * i + 0] * 0.5f + 0.5f;
    const float p01y = pts[3 * i + 1] * 0.5f + 0.5f;
    const float p01z = pts[3 * i + 2] * 0.5f + 0.5f;
    atomicAdd(&hist[bucket_key(p01x, p01y, p01z)], 1u);
}

__global__ __launch_bounds__(1024)
void HashGrid_scan_kernel(unsigned* __restrict__ h)
{
    __shared__ unsigned ps[1024];
    const int t = threadIdx.x;
    unsigned sum = 0;
    for (int k = 0; k < 32; ++k) sum += h[t * 32 + k];
    ps[t] = sum;
    __syncthreads();
    for (int off = 1; off < 1024; off <<= 1) {
        unsigned v = ps[t];
        unsigned add = (t >= off) ? ps[t - off] : 0u;
        __syncthreads();
        ps[t] = v + add;
        __syncthreads();
    }
    unsigned run = (t == 0) ? 0u : ps[t - 1];
    for (int k = 0; k < 32; ++k) {
        const unsigned c = h[t * 32 + k];
        h[t * 32 + k] = run;
        run += c;
    }
}

__global__ __launch_bounds__(256)
void HashGrid_scatter_kernel(const float* __restrict__ pts, unsigned* __restrict__ off,
                             float4* __restrict__ sorted, int n)
{
    const int i = blockIdx.x * 256 + threadIdx.x;
    if (i >= n) return;
    const float x = pts[3 * i + 0], y = pts[3 * i + 1], z = pts[3 * i + 2];
    const float p01x = x * 0.5f + 0.5f;
    const float p01y = y * 0.5f + 0.5f;
    const float p01z = z * 0.5f + 0.5f;
    const unsigned pos = atomicAdd(&off[bucket_key(p01x, p01y, p01z)], 1u);
    sorted[pos] = make_float4(x, y, z, __uint_as_float((unsigned)i));
}

// ---- main (sorted) ----
__global__ __launch_bounds__(256, 8)
void HashGrid_88278757802387_kernel(const float4* __restrict__ sorted,
                                    const unsigned short* __restrict__ ws,
                                    float* __restrict__ out,
                                    int n, int res7)
{
    const int i = blockIdx.x * 256 + threadIdx.x;
    if (i >= n) return;
    const float4 p = sorted[i];
    const float p01x = p.x * 0.5f + 0.5f;
    const float p01y = p.y * 0.5f + 0.5f;
    const float p01z = p.z * 0.5f + 0.5f;
    const unsigned oidx = __float_as_uint(p.w);

    // coarse LODs: plain gathers; sorted waves coalesce at the TA
    W3 f0, f1, f2, f3;
    I8 g0 = idx8m<4913u  >(p01x, p01y, p01z, 17, f0);
    I8 g1 = idx8m<19683u >(p01x, p01y, p01z, 27, f1);
    I8 g2 = idx8m<85184u >(p01x, p01y, p01z, 44, f2);
    I8 g3 = idx8m<357911u>(p01x, p01y, p01z, 71, f3);
    R8 r0 = gather8(ws + O0, g0);
    R8 r1 = gather8(ws + O1, g1);
    R8 r2 = gather8(ws + O2, g2);
    R8 r3 = gather8(ws + O3, g3);
    float acc = acc8(r0, f0) + acc8(r1, f1) + acc8(r2, f2) + acc8(r3, f3);

    // fine LODs: x-pair merged
    acc += lod_merged<0>(p01x, p01y, p01z, 116,  ws + O4);
    acc += lod_merged<0>(p01x, p01y, p01z, 191,  ws + O5);
    acc += lod_merged<0>(p01x, p01y, p01z, 313,  ws + O6);
    acc += lod_merged<0>(p01x, p01y, p01z, res7, ws + O7);

    out[oidx] = acc;
}

// ---- direct (R12) tier ----
__global__ __launch_bounds__(1024, 4)
void HashGrid_direct_kernel(const float* __restrict__ pts,
                            const float* __restrict__ codebook,
                            const unsigned short* __restrict__ ws,
                            float* __restrict__ out,
                            int n, int res7)
{
    __shared__ unsigned short sm[S0 + S1];
    for (int j = threadIdx.x; j < S0 + S1; j += 1024)
        sm[j] = f32_to_bf16_rne(j < S0 ? codebook[j] : codebook[CB_STRIDE + (j - S0)]);
    __syncthreads();

    const int i = blockIdx.x * 1024 + threadIdx.x;
    if (i >= n) return;

    const float p01x = pts[3 * i + 0] * 0.5f + 0.5f;
    const float p01y = pts[3 * i + 1] * 0.5f + 0.5f;
    const float p01z = pts[3 * i + 2] * 0.5f + 0.5f;

    W3 fB, fL0, fL1;
    I8 oB = idx8m<357911u>(p01x, p01y, p01z, 71, fB);
    R8 rB = gather8(ws + O3, oB);

    float acc = lod_merged<1>(p01x, p01y, p01z, 44,   ws + O2);
    acc      += lod_merged<0>(p01x, p01y, p01z, 116,  ws + O4);
    acc      += lod_merged<0>(p01x, p01y, p01z, 191,  ws + O5);
    acc      += lod_merged<0>(p01x, p01y, p01z, 313,  ws + O6);
    acc      += lod_merged<0>(p01x, p01y, p01z, res7, ws + O7);

    I8 oL0 = idx8m<4913u >(p01x, p01y, p01z, 17, fL0);
    I8 oL1 = idx8m<19683u>(p01x, p01y, p01z, 27, fL1);
    R8 rL0 = gather8(sm, oL0);
    R8 rL1 = gather8(sm + S0, oL1);
    acc += acc8(rL0, fL0) + acc8(rL1, fL1);
    acc += acc8(rB, fB);

    out[i] = acc;
}

// fallback (no ws): per-LOD f32 path straight from codebook
__global__ __launch_bounds__(1024, 4)
void HashGrid_fallback_kernel(const float* __restrict__ pts,
                              const float* __restrict__ codebook,
                              float* __restrict__ out,
                              int n, int res7)
{
    const int i = blockIdx.x * 1024 + threadIdx.x;
    if (i >= n) return;
    const float p01x = pts[3 * i + 0] * 0.5f + 0.5f;
    const float p01y = pts[3 * i + 1] * 0.5f + 0.5f;
    const float p01z = pts[3 * i + 2] * 0.5f + 0.5f;
    float acc = 0.0f;
    const int      reslist[8]  = {17, 27, 44, 71, 116, 191, 313, res7};
    const unsigned sizelist[8] = {4913u, 19683u, 85184u, 357911u, 524288u, 524288u, 524288u, 524288u};
    for (int l = 0; l < 8; ++l) {
        const int res = reslist[l];
        const unsigned size = sizelist[l];
        const float rm1 = (float)(res - 1);
        float xx = p01x * rm1, yy = p01y * rm1, zz = p01z * rm1;
        float fx = fminf(fmaxf(floorf(xx), 0.0f), (float)(res - 2));
        float fy = fminf(fmaxf(floorf(yy), 0.0f), (float)(res - 2));
        float fz = fminf(fmaxf(floorf(zz), 0.0f), (float)(res - 2));
        const float frx = xx - fx, fry = yy - fy, frz = zz - fz;
        const unsigned ix = (unsigned)(int)fx, iy = (unsigned)(int)fy, iz = (unsigned)(int)fz;
        const unsigned hy0 = iy * 2654435761u, hy1 = hy0 + 2654435761u;
        const unsigned hz0 = iz * 805459861u,  hz1 = hz0 + 805459861u;
        const unsigned o0 = (ix ^ hy0 ^ hz0) % size,      o1 = (ix ^ hy0 ^ hz1) % size;
        const unsigned o2 = (ix ^ hy1 ^ hz0) % size,      o3 = (ix ^ hy1 ^ hz1) % size;
        const unsigned o4 = ((ix+1u) ^ hy0 ^ hz0) % size, o5 = ((ix+1u) ^ hy0 ^ hz1) % size;
        const unsigned o6 = ((ix+1u) ^ hy1 ^ hz0) % size, o7 = ((ix+1u) ^ hy1 ^ hz1) % size;
        const float* tab = codebook + (unsigned)l * CB_STRIDE;
        const float wx1 = frx, wx0 = 1.0f - frx;
        const float wy1 = fry, wy0 = 1.0f - fry;
        const float wz1 = frz, wz0 = 1.0f - frz;
        const float w00 = wy0*wz0, w01 = wy0*wz1, w10 = wy1*wz0, w11 = wy1*wz1;
        acc += wx0 * (tab[o0]*w00 + tab[o1]*w01 + tab[o2]*w10 + tab[o3]*w11)
             + wx1 * (tab[o4]*w00 + tab[o5]*w01 + tab[o6]*w10 + tab[o7]*w11);
    }
    out[i] = acc;
}

extern "C" void kernel_launch(void* const* d_in, const int* in_sizes, int n_in,
                              void* d_out, int out_size, void* d_ws, size_t ws_size,
                              hipStream_t stream)
{
    const float* pts      = (const float*)d_in[0];
    const float* codebook = (const float*)d_in[1];
    float* out            = (float*)d_out;
    const int n = in_sizes[0] / 3;

    // numpy-matching LOD7 resolution (16*b^7 sits ~1e-12 from 512.0)
    const double b = exp((log(512.0) - log(16.0)) / 7.0);
    const int res7 = (int)(1.0 + floor(16.0 * pow(b, 7.0)));

    const int blocks256  = (n + 255) / 256;
    const int blocks1024 = (n + 1023) / 1024;

    if (d_ws != nullptr && ws_size >= ws_full_bytes(n)) {
        unsigned short* ws = (unsigned short*)d_ws;
        unsigned* hist = (unsigned*)((char*)d_ws + OFF_H);
        float4* sorted = (float4*)((char*)d_ws + OFF_P);
        hipLaunchKernelGGL(HashGrid_convert_kernel, dim3(512, 8), dim3(1024),
                           0, stream, codebook, ws);
        hipLaunchKernelGGL(HashGrid_zero_hist, dim3(NB / 1024), dim3(1024),
                           0, stream, hist);
        hipLaunchKernelGGL(HashGrid_hist_kernel, dim3(blocks256), dim3(256),
                           0, stream, pts, hist, n);
        hipLaunchKernelGGL(HashGrid_scan_kernel, dim3(1), dim3(1024),
                           0, stream, hist);
        hipLaunchKernelGGL(HashGrid_scatter_kernel, dim3(blocks256), dim3(256),
                           0, stream, pts, hist, sorted, n);
        hipLaunchKernelGGL(HashGrid_88278757802387_kernel, dim3(blocks256), dim3(256),
                           0, stream, sorted, ws, out, n, res7);
    } else if (d_ws != nullptr && ws_size >= WS_MID_BYTES) {
        unsigned short* ws = (unsigned short*)d_ws;
        hipLaunchKernelGGL(HashGrid_convert_kernel, dim3(512, 8), dim3(1024),
                           0, stream, codebook, ws);
        hipLaunchKernelGGL(HashGrid_direct_kernel, dim3(blocks1024), dim3(1024),
                           0, stream, pts, codebook, ws, out, n, res7);
    } else {
        hipLaunchKernelGGL(HashGrid_fallback_kernel, dim3(blocks1024), dim3(1024),
                           0, stream, pts, codebook, out, n, res7);
    }
}

// Round 14
// 352.539 us; speedup vs baseline: 1.6374x; 1.6374x over previous
//
#include <hip/hip_runtime.h>
#include <math.h>

// HashGrid: 8 LODs, hashed trilinear interp, 1 feature/entry, summed over LODs.
// LODS  = [17, 27, 44, 71, 116, 191, 313, res7(host-computed, 512 or 513)]
// SIZES = [4913, 19683, 85184, 357911, 2^19, 2^19, 2^19, 2^19]
// codebook layout: [8][524288][1] float32.
//
// R14 = R12 + partial-LDS LOD2. Model: cost ~ 2.7 cyc per L2-MISSING random
// address (cache-hot addrs cheap: R7 vs R5). Expensive addrs 38 -> 34.3 by
// staging a 52K-entry prefix of LOD2 (104 KB, 61% of its uniform hash
// traffic) into LDS next to LOD0/1. LDS 149.6 KB -> 1 block/CU, 16 waves
// (occupancy-insensitive at the wall: R5/R7). Per-lane predicated LDS/global
// select; both sides exec-masked, discarded side harmless.
// R13's sort: main 311us but prep ~266us -> net loss, reverted.

static constexpr unsigned CB_STRIDE = 524288u;
static constexpr int S0 = 4913;    // 17^3
static constexpr int S1 = 19683;   // 27^3
static constexpr int T2  = 52000;  // LOD2 entries staged in LDS (even)
static constexpr int T2P = 26000;  // staged dword pairs
// ws (bf16) element offsets for LOD2..7 (all EVEN, tables 4B-aligned)
static constexpr unsigned WO2 = 0;        // 85184
static constexpr unsigned WO3 = 85184;    // 357911
static constexpr unsigned WO4 = 443104;   // 524288
static constexpr unsigned WO5 = 967392;
static constexpr unsigned WO6 = 1491680;
static constexpr unsigned WO7 = 2015968;  // -> end 2540256 u16
static constexpr size_t WS_NEED_BYTES = 2540256u * 2u;  // 5.08 MB

__device__ __forceinline__ unsigned short f32_to_bf16_rne(float f) {
    unsigned u = __float_as_uint(f);
    u = (u + 0x7FFFu + ((u >> 16) & 1u)) >> 16;
    return (unsigned short)u;
}
__device__ __forceinline__ float bf16_to_f32(unsigned short s) {
    return __uint_as_float(((unsigned)s) << 16);
}

struct I8 { unsigned a0, a1, a2, a3, a4, a5, a6, a7; };
struct R8 { unsigned short v0, v1, v2, v3, v4, v5, v6, v7; };
struct W3 { float x, y, z; };

template <unsigned SIZE>
__device__ __forceinline__ I8 idx8m(float p01x, float p01y, float p01z, int res, W3& fr)
{
    const float rm1 = (float)(res - 1);
    float xx = p01x * rm1, yy = p01y * rm1, zz = p01z * rm1;
    const float cmax = (float)(res - 2);
    float fx = fminf(fmaxf(floorf(xx), 0.0f), cmax);
    float fy = fminf(fmaxf(floorf(yy), 0.0f), cmax);
    float fz = fminf(fmaxf(floorf(zz), 0.0f), cmax);
    fr.x = xx - fx; fr.y = yy - fy; fr.z = zz - fz;
    const unsigned ix = (unsigned)(int)fx;
    const unsigned iy = (unsigned)(int)fy;
    const unsigned iz = (unsigned)(int)fz;
    const unsigned hy0 = iy * 2654435761u, hy1 = hy0 + 2654435761u;
    const unsigned hz0 = iz * 805459861u,  hz1 = hz0 + 805459861u;
    I8 o;
    o.a0 = (ix ^ hy0 ^ hz0) % SIZE;        o.a1 = (ix ^ hy0 ^ hz1) % SIZE;
    o.a2 = (ix ^ hy1 ^ hz0) % SIZE;        o.a3 = (ix ^ hy1 ^ hz1) % SIZE;
    o.a4 = ((ix+1u) ^ hy0 ^ hz0) % SIZE;   o.a5 = ((ix+1u) ^ hy0 ^ hz1) % SIZE;
    o.a6 = ((ix+1u) ^ hy1 ^ hz0) % SIZE;   o.a7 = ((ix+1u) ^ hy1 ^ hz1) % SIZE;
    return o;
}

__device__ __forceinline__ R8 gather8(const unsigned short* __restrict__ t, I8 o)
{
    R8 r;
    r.v0 = t[o.a0]; r.v1 = t[o.a1]; r.v2 = t[o.a2]; r.v3 = t[o.a3];
    r.v4 = t[o.a4]; r.v5 = t[o.a5]; r.v6 = t[o.a6]; r.v7 = t[o.a7];
    return r;
}

__device__ __forceinline__ float acc8(R8 r, W3 f)
{
    const float wx1 = f.x, wx0 = 1.0f - f.x;
    const float wy1 = f.y, wy0 = 1.0f - f.y;
    const float wz1 = f.z, wz0 = 1.0f - f.z;
    const float w00 = wy0 * wz0, w01 = wy0 * wz1;
    const float w10 = wy1 * wz0, w11 = wy1 * wz1;
    const float sx0 = bf16_to_f32(r.v0) * w00 + bf16_to_f32(r.v1) * w01
                    + bf16_to_f32(r.v2) * w10 + bf16_to_f32(r.v3) * w11;
    const float sx1 = bf16_to_f32(r.v4) * w00 + bf16_to_f32(r.v5) * w01
                    + bf16_to_f32(r.v6) * w10 + bf16_to_f32(r.v7) * w11;
    return wx0 * sx0 + wx1 * sx1;
}

// pow2 2^19 x-pair dword merge (R10)
__device__ __forceinline__ float lod_pow2(float p01x, float p01y, float p01z,
                                          int res, const unsigned short* __restrict__ t)
{
    const float rm1 = (float)(res - 1);
    float xx = p01x * rm1, yy = p01y * rm1, zz = p01z * rm1;
    const float cmax = (float)(res - 2);
    float fx = fminf(fmaxf(floorf(xx), 0.0f), cmax);
    float fy = fminf(fmaxf(floorf(yy), 0.0f), cmax);
    float fz = fminf(fmaxf(floorf(zz), 0.0f), cmax);
    const float frx = xx - fx, fry = yy - fy, frz = zz - fz;
    const unsigned ix = (unsigned)(int)fx;
    const unsigned iy = (unsigned)(int)fy;
    const unsigned iz = (unsigned)(int)fz;

    const unsigned hy0 = iy * 2654435761u, hy1 = hy0 + 2654435761u;
    const unsigned hz0 = iz * 805459861u,  hz1 = hz0 + 805459861u;

    const unsigned h00 = ix ^ hy0 ^ hz0;
    const unsigned h01 = ix ^ hy0 ^ hz1;
    const unsigned h10 = ix ^ hy1 ^ hz0;
    const unsigned h11 = ix ^ hy1 ^ hz1;

    const unsigned bm = 524286u;  // (2^19-1) & ~1
    const unsigned E00 = h00 & bm, E01 = h01 & bm, E10 = h10 & bm, E11 = h11 & bm;

    const unsigned* t32 = reinterpret_cast<const unsigned*>(t);
    const unsigned p00 = t32[E00 >> 1];
    const unsigned p01 = t32[E01 >> 1];
    const unsigned p10 = t32[E10 >> 1];
    const unsigned p11 = t32[E11 >> 1];

    const bool oddx = (ix & 1u) != 0u;
    unsigned short q00 = 0, q01 = 0, q10 = 0, q11 = 0;
    if (oddx) {
        const unsigned g = ix + 1u, m = 524287u;
        q00 = t[(g ^ hy0 ^ hz0) & m]; q01 = t[(g ^ hy0 ^ hz1) & m];
        q10 = t[(g ^ hy1 ^ hz0) & m]; q11 = t[(g ^ hy1 ^ hz1) & m];
    }

    const unsigned s00 = h00 & 1u, s01 = h01 & 1u, s10 = h10 & 1u, s11 = h11 & 1u;
    const float a00 = bf16_to_f32((unsigned short)(s00 ? (p00 >> 16) : (p00 & 0xffffu)));
    const float a01 = bf16_to_f32((unsigned short)(s01 ? (p01 >> 16) : (p01 & 0xffffu)));
    const float a10 = bf16_to_f32((unsigned short)(s10 ? (p10 >> 16) : (p10 & 0xffffu)));
    const float a11 = bf16_to_f32((unsigned short)(s11 ? (p11 >> 16) : (p11 & 0xffffu)));
    const float b00 = bf16_to_f32(oddx ? q00 : (unsigned short)(s00 ? (p00 & 0xffffu) : (p00 >> 16)));
    const float b01 = bf16_to_f32(oddx ? q01 : (unsigned short)(s01 ? (p01 & 0xffffu) : (p01 >> 16)));
    const float b10 = bf16_to_f32(oddx ? q10 : (unsigned short)(s10 ? (p10 & 0xffffu) : (p10 >> 16)));
    const float b11 = bf16_to_f32(oddx ? q11 : (unsigned short)(s11 ? (p11 & 0xffffu) : (p11 >> 16)));

    const float wx1 = frx, wx0 = 1.0f - frx;
    const float wy1 = fry, wy0 = 1.0f - fry;
    const float wz1 = frz, wz0 = 1.0f - frz;
    const float w00 = wy0 * wz0, w01 = wy0 * wz1;
    const float w10 = wy1 * wz0, w11 = wy1 * wz1;
    const float sx0 = a00 * w00 + a01 * w01 + a10 * w10 + a11 * w11;
    const float sx1 = b00 * w00 + b01 * w01 + b10 * w10 + b11 * w11;
    return wx0 * sx0 + wx1 * sx1;
}

// LOD2 (size 85184, even) x-pair merge with partial-LDS: pairs < T2P and
// odd-x entries < T2 served from LDS, rest from global. Per-lane select.
__device__ __forceinline__ float lod2_split(float p01x, float p01y, float p01z,
                                            const unsigned short* __restrict__ t,
                                            const unsigned short* sl)
{
    const float rm1 = 43.0f;  // res 44
    float xx = p01x * rm1, yy = p01y * rm1, zz = p01z * rm1;
    const float cmax = 42.0f;
    float fx = fminf(fmaxf(floorf(xx), 0.0f), cmax);
    float fy = fminf(fmaxf(floorf(yy), 0.0f), cmax);
    float fz = fminf(fmaxf(floorf(zz), 0.0f), cmax);
    const float frx = xx - fx, fry = yy - fy, frz = zz - fz;
    const unsigned ix = (unsigned)(int)fx;
    const unsigned iy = (unsigned)(int)fy;
    const unsigned iz = (unsigned)(int)fz;

    const unsigned hy0 = iy * 2654435761u, hy1 = hy0 + 2654435761u;
    const unsigned hz0 = iz * 805459861u,  hz1 = hz0 + 805459861u;

    const unsigned h00 = ix ^ hy0 ^ hz0;
    const unsigned h01 = ix ^ hy0 ^ hz1;
    const unsigned h10 = ix ^ hy1 ^ hz0;
    const unsigned h11 = ix ^ hy1 ^ hz1;

    const unsigned P00 = ((h00 & ~1u) % 85184u) >> 1;
    const unsigned P01 = ((h01 & ~1u) % 85184u) >> 1;
    const unsigned P10 = ((h10 & ~1u) % 85184u) >> 1;
    const unsigned P11 = ((h11 & ~1u) % 85184u) >> 1;

    const unsigned* t32 = reinterpret_cast<const unsigned*>(t);
    const unsigned* s32 = reinterpret_cast<const unsigned*>(sl);
    const unsigned p00 = (P00 < (unsigned)T2P) ? s32[P00] : t32[P00];
    const unsigned p01 = (P01 < (unsigned)T2P) ? s32[P01] : t32[P01];
    const unsigned p10 = (P10 < (unsigned)T2P) ? s32[P10] : t32[P10];
    const unsigned p11 = (P11 < (unsigned)T2P) ? s32[P11] : t32[P11];

    const bool oddx = (ix & 1u) != 0u;
    unsigned short q00 = 0, q01 = 0, q10 = 0, q11 = 0;
    if (oddx) {
        const unsigned g = ix + 1u;
        const unsigned j00 = (g ^ hy0 ^ hz0) % 85184u;
        const unsigned j01 = (g ^ hy0 ^ hz1) % 85184u;
        const unsigned j10 = (g ^ hy1 ^ hz0) % 85184u;
        const unsigned j11 = (g ^ hy1 ^ hz1) % 85184u;
        q00 = (j00 < (unsigned)T2) ? sl[j00] : t[j00];
        q01 = (j01 < (unsigned)T2) ? sl[j01] : t[j01];
        q10 = (j10 < (unsigned)T2) ? sl[j10] : t[j10];
        q11 = (j11 < (unsigned)T2) ? sl[j11] : t[j11];
    }

    const unsigned s00 = h00 & 1u, s01 = h01 & 1u, s10 = h10 & 1u, s11 = h11 & 1u;
    const float a00 = bf16_to_f32((unsigned short)(s00 ? (p00 >> 16) : (p00 & 0xffffu)));
    const float a01 = bf16_to_f32((unsigned short)(s01 ? (p01 >> 16) : (p01 & 0xffffu)));
    const float a10 = bf16_to_f32((unsigned short)(s10 ? (p10 >> 16) : (p10 & 0xffffu)));
    const float a11 = bf16_to_f32((unsigned short)(s11 ? (p11 >> 16) : (p11 & 0xffffu)));
    const float b00 = bf16_to_f32(oddx ? q00 : (unsigned short)(s00 ? (p00 & 0xffffu) : (p00 >> 16)));
    const float b01 = bf16_to_f32(oddx ? q01 : (unsigned short)(s01 ? (p01 & 0xffffu) : (p01 >> 16)));
    const float b10 = bf16_to_f32(oddx ? q10 : (unsigned short)(s10 ? (p10 & 0xffffu) : (p10 >> 16)));
    const float b11 = bf16_to_f32(oddx ? q11 : (unsigned short)(s11 ? (p11 & 0xffffu) : (p11 >> 16)));

    const float wx1 = frx, wx0 = 1.0f - frx;
    const float wy1 = fry, wy0 = 1.0f - fry;
    const float wz1 = frz, wz0 = 1.0f - frz;
    const float w00 = wy0 * wz0, w01 = wy0 * wz1;
    const float w10 = wy1 * wz0, w11 = wy1 * wz1;
    const float sx0 = a00 * w00 + a01 * w01 + a10 * w10 + a11 * w11;
    const float sx1 = b00 * w00 + b01 * w01 + b10 * w10 + b11 * w11;
    return wx0 * sx0 + wx1 * sx1;
}

// prep: convert LOD2..7 table prefixes to bf16 in ws
__global__ __launch_bounds__(1024)
void HashGrid_convert_kernel(const float* __restrict__ codebook,
                             unsigned short* __restrict__ ws)
{
    const int lod = blockIdx.y;  // 0..5 -> LOD2..7
    const int sizes[6] = {85184, 357911, 524288, 524288, 524288, 524288};
    const unsigned offs[6] = {WO2, WO3, WO4, WO5, WO6, WO7};
    const int idx = blockIdx.x * 1024 + threadIdx.x;
    if (idx < sizes[lod])
        ws[offs[lod] + idx] = f32_to_bf16_rne(codebook[(unsigned)(lod + 2) * CB_STRIDE + idx]);
}

__global__ __launch_bounds__(1024, 4)
void HashGrid_88278757802387_kernel(const float* __restrict__ pts,
                                    const float* __restrict__ codebook,
                                    const unsigned short* __restrict__ ws,
                                    float* __restrict__ out,
                                    int n, int res7)
{
    __shared__ unsigned short sm[S0 + S1 + T2];  // 149.6 KB -> 1 block/CU
    for (int j = threadIdx.x; j < S0 + S1; j += 1024)
        sm[j] = f32_to_bf16_rne(j < S0 ? codebook[j] : codebook[CB_STRIDE + (j - S0)]);
    {   // LOD2 prefix from the bf16 ws image, 16B vectorized (6500 uint4)
        uint4* dst = reinterpret_cast<uint4*>(sm + S0 + S1);
        const uint4* src = reinterpret_cast<const uint4*>(ws + WO2);
        for (int j = threadIdx.x; j < T2 * 2 / 16; j += 1024) dst[j] = src[j];
    }
    __syncthreads();

    const int i = blockIdx.x * 1024 + threadIdx.x;
    if (i >= n) return;

    const float p01x = pts[3 * i + 0] * 0.5f + 0.5f;
    const float p01y = pts[3 * i + 1] * 0.5f + 0.5f;
    const float p01z = pts[3 * i + 2] * 0.5f + 0.5f;

    // LOD3 (odd size, unmergeable): issue its 8 u16 gathers early
    W3 fB, fL0, fL1;
    I8 oB = idx8m<357911u>(p01x, p01y, p01z, 71, fB);
    R8 rB = gather8(ws + WO3, oB);

    // LOD2: x-pair merged + partial LDS
    float acc = lod2_split(p01x, p01y, p01z, ws + WO2, sm + S0 + S1);

    // pow2 LODs: x-pair merged
    acc += lod_pow2(p01x, p01y, p01z, 116,  ws + WO4);
    acc += lod_pow2(p01x, p01y, p01z, 191,  ws + WO5);
    acc += lod_pow2(p01x, p01y, p01z, 313,  ws + WO6);
    acc += lod_pow2(p01x, p01y, p01z, res7, ws + WO7);

    // LDS LODs 0/1
    I8 oL0 = idx8m<4913u >(p01x, p01y, p01z, 17, fL0);
    I8 oL1 = idx8m<19683u>(p01x, p01y, p01z, 27, fL1);
    R8 rL0 = gather8(sm, oL0);
    R8 rL1 = gather8(sm + S0, oL1);
    acc += acc8(rL0, fL0) + acc8(rL1, fL1);

    // consume LOD3
    acc += acc8(rB, fB);

    out[i] = acc;
}

// fallback (no ws): per-LOD f32 path straight from codebook
__global__ __launch_bounds__(1024, 4)
void HashGrid_fallback_kernel(const float* __restrict__ pts,
                              const float* __restrict__ codebook,
                              float* __restrict__ out,
                              int n, int res7)
{
    const int i = blockIdx.x * 1024 + threadIdx.x;
    if (i >= n) return;
    const float p01x = pts[3 * i + 0] * 0.5f + 0.5f;
    const float p01y = pts[3 * i + 1] * 0.5f + 0.5f;
    const float p01z = pts[3 * i + 2] * 0.5f + 0.5f;
    float acc = 0.0f;
    const int      reslist[8]  = {17, 27, 44, 71, 116, 191, 313, res7};
    const unsigned sizelist[8] = {4913u, 19683u, 85184u, 357911u, 524288u, 524288u, 524288u, 524288u};
    for (int l = 0; l < 8; ++l) {
        const int res = reslist[l];
        const unsigned size = sizelist[l];
        const float rm1 = (float)(res - 1);
        float xx = p01x * rm1, yy = p01y * rm1, zz = p01z * rm1;
        float fx = fminf(fmaxf(floorf(xx), 0.0f), (float)(res - 2));
        float fy = fminf(fmaxf(floorf(yy), 0.0f), (float)(res - 2));
        float fz = fminf(fmaxf(floorf(zz), 0.0f), (float)(res - 2));
        const float frx = xx - fx, fry = yy - fy, frz = zz - fz;
        const unsigned ix = (unsigned)(int)fx, iy = (unsigned)(int)fy, iz = (unsigned)(int)fz;
        const unsigned hy0 = iy * 2654435761u, hy1 = hy0 + 2654435761u;
        const unsigned hz0 = iz * 805459861u,  hz1 = hz0 + 805459861u;
        const unsigned o0 = (ix ^ hy0 ^ hz0) % size,      o1 = (ix ^ hy0 ^ hz1) % size;
        const unsigned o2 = (ix ^ hy1 ^ hz0) % size,      o3 = (ix ^ hy1 ^ hz1) % size;
        const unsigned o4 = ((ix+1u) ^ hy0 ^ hz0) % size, o5 = ((ix+1u) ^ hy0 ^ hz1) % size;
        const unsigned o6 = ((ix+1u) ^ hy1 ^ hz0) % size, o7 = ((ix+1u) ^ hy1 ^ hz1) % size;
        const float* tab = codebook + (unsigned)l * CB_STRIDE;
        const float wx1 = frx, wx0 = 1.0f - frx;
        const float wy1 = fry, wy0 = 1.0f - fry;
        const float wz1 = frz, wz0 = 1.0f - frz;
        const float w00 = wy0*wz0, w01 = wy0*wz1, w10 = wy1*wz0, w11 = wy1*wz1;
        acc += wx0 * (tab[o0]*w00 + tab[o1]*w01 + tab[o2]*w10 + tab[o3]*w11)
             + wx1 * (tab[o4]*w00 + tab[o5]*w01 + tab[o6]*w10 + tab[o7]*w11);
    }
    out[i] = acc;
}

extern "C" void kernel_launch(void* const* d_in, const int* in_sizes, int n_in,
                              void* d_out, int out_size, void* d_ws, size_t ws_size,
                              hipStream_t stream)
{
    const float* pts      = (const float*)d_in[0];
    const float* codebook = (const float*)d_in[1];
    float* out            = (float*)d_out;
    const int n = in_sizes[0] / 3;

    // numpy-matching LOD7 resolution (16*b^7 sits ~1e-12 from 512.0)
    const double b = exp((log(512.0) - log(16.0)) / 7.0);
    const int res7 = (int)(1.0 + floor(16.0 * pow(b, 7.0)));

    const bool use_ws = (d_ws != nullptr) && (ws_size >= WS_NEED_BYTES);
    const int blocks = (n + 1023) / 1024;

    if (use_ws) {
        unsigned short* ws = (unsigned short*)d_ws;
        hipLaunchKernelGGL(HashGrid_convert_kernel, dim3(512, 6), dim3(1024),
                           0, stream, codebook, ws);
        hipLaunchKernelGGL(HashGrid_88278757802387_kernel, dim3(blocks), dim3(1024),
                           0, stream, pts, codebook, ws, out, n, res7);
    } else {
        hipLaunchKernelGGL(HashGrid_fallback_kernel, dim3(blocks), dim3(1024),
                           0, stream, pts, codebook, out, n, res7);
    }
}